// Round 5
// baseline (642.600 us; speedup 1.0000x reference)
//
#include <hip/hip_runtime.h>
#include <hip/hip_cooperative_groups.h>

#define D 128
#define KOUT 100
#define CHUNK 4096   // edges per pass-1 block

namespace cg = cooperative_groups;

typedef __attribute__((ext_vector_type(8))) short short8;
typedef __attribute__((ext_vector_type(4))) float floatx4;
typedef __attribute__((ext_vector_type(4))) unsigned int uintx4;

// ---------------- bf16 pack/unpack helpers ----------------
__device__ inline float bf_lo(unsigned int u) { return __uint_as_float(u << 16); }
__device__ inline float bf_hi(unsigned int u) { return __uint_as_float(u & 0xFFFF0000u); }

__device__ inline unsigned int bf_round(float a) {      // f32 -> bf16 bits (RNE)
    unsigned int ua = __float_as_uint(a);
    return (ua + 0x7FFFu + ((ua >> 16) & 1u)) >> 16;
}
__device__ inline unsigned int pack_bf(float a, float b) {
    return bf_round(a) | (bf_round(b) << 16);
}

// ---------------- args ----------------
struct MegaArgs {
    const float* x; const int* ei;
    const float* W1; const float* b1; const float* W2; const float* b2;
    const float* Wa; const float* ba;
    float* out;
    float* dinv; int* rowptr; int* bcur; unsigned int* bdata; int* csr;
    unsigned short* Wf1; unsigned short* Wf2; unsigned short* WfA; float* bpad;
    unsigned int* HbA; unsigned int* HbB;
    int N, E, nbuck, cap, nbP1, nbGemm;
};

// ---------------- P0: weight prep + zeroing + sentinel ----------------
// Wfrag[(kt*8+ct)*64 + lane][j] = W[kt*32 + (lane>>4)*8 + j][ct*16 + (lane&15)]
// H tables: [N+1 rows][64 uint (=128 bf16 feats, 256 B)]; row N = zero row.
__device__ void prep_body(const MegaArgs& A) {
    int idx = blockIdx.x * blockDim.x + threadIdx.x;
    if (idx < 3 * 16384) {
        int m = idx / 16384;
        int e = idx & 16383;
        int j = e & 7, lane = (e >> 3) & 63, ct = (e >> 9) & 7, kt = e >> 12;
        int k = kt * 32 + (lane >> 4) * 8 + j;
        int col = ct * 16 + (lane & 15);
        float val;
        unsigned short* dst;
        if (m == 0)      { val = A.W1[k * 128 + col]; dst = A.Wf1; }
        else if (m == 1) { val = A.W2[k * 128 + col]; dst = A.Wf2; }
        else             { val = (col < KOUT) ? A.Wa[k * KOUT + col] : 0.f; dst = A.WfA; }
        dst[e] = (unsigned short)bf_round(val);
    }
    if (idx < 128) A.bpad[idx] = (idx < KOUT) ? A.ba[idx] : 0.f;
    if (idx < 256) A.bcur[idx] = 0;
    if (idx < 64) {
        A.HbA[(size_t)A.N * 64 + idx] = 0u;
        A.HbB[(size_t)A.N * 64 + idx] = 0u;
    }
    if (idx == 256) A.rowptr[A.N] = A.E;   // sentinel
}

// ---------------- P1: bucket radix partition ----------------
// bucket = dst >> 8; packed record: bits[23:0]=src, bits[31:24]=dst&255
__device__ void pass1_phase(const MegaArgs& A, float* lds) {
    int* hist = (int*)lds;
    int* sc   = hist + 256;
    int* pfx  = sc + 256;
    int* cur  = pfx + 256;
    int* gbase = cur + 256;
    unsigned int* lbuf = (unsigned int*)(gbase + 256);     // 16 KB
    unsigned char* bkt = (unsigned char*)(lbuf + CHUNK);   // 4 KB

    int tid = threadIdx.x;
    for (int ch = blockIdx.x; ch < A.nbP1; ch += gridDim.x) {
        int base = ch * CHUNK;
        int cnt = A.E - base; if (cnt > CHUNK) cnt = CHUNK;

        __syncthreads();
        hist[tid] = 0;
        __syncthreads();

        int src[CHUNK / 256];
        int dst[CHUNK / 256];
#pragma unroll
        for (int q = 0; q < CHUNK / 256; q++) {
            int li = tid + q * 256;
            if (li < cnt) {
                src[q] = A.ei[base + li];
                dst[q] = A.ei[A.E + base + li];
                atomicAdd(&hist[dst[q] >> 8], 1);
            }
        }
        __syncthreads();

        int v = hist[tid];
        sc[tid] = v;
        __syncthreads();
        for (int off = 1; off < 256; off <<= 1) {
            int t = (tid >= off) ? sc[tid - off] : 0;
            __syncthreads();
            sc[tid] += t;
            __syncthreads();
        }
        int excl = sc[tid] - v;
        pfx[tid] = excl;
        cur[tid] = excl;
        gbase[tid] = 0;
        if (tid < A.nbuck && v > 0) gbase[tid] = atomicAdd(&A.bcur[tid], v);
        __syncthreads();

#pragma unroll
        for (int q = 0; q < CHUNK / 256; q++) {
            int li = tid + q * 256;
            if (li < cnt) {
                int b = dst[q] >> 8;
                int p = atomicAdd(&cur[b], 1);
                lbuf[p] = (unsigned int)src[q] | ((unsigned int)(dst[q] & 255) << 24);
                bkt[p] = (unsigned char)b;
            }
        }
        __syncthreads();

        for (int p = tid; p < cnt; p += 256) {
            int b = bkt[p];
            A.bdata[(size_t)b * A.cap + gbase[b] + (p - pfx[b])] = lbuf[p];
        }
    }
}

// ---------------- P2: dinv + rowptr + csr scatter ----------------
__device__ void build_phase(const MegaArgs& A, float* lds) {
    int* cnts = (int*)lds;
    int* sc   = cnts + 256;
    int* cur  = sc + 256;
    int* pbb  = cur + 256;     // bbase

    int tid = threadIdx.x;
    for (int b = blockIdx.x; b < A.nbuck; b += gridDim.x) {
        __syncthreads();
        if (tid == 0) pbb[0] = 0;
        cnts[tid] = 0;
        __syncthreads();

        int part = 0;
        for (int t = tid; t < b; t += 256) part += A.bcur[t];
#pragma unroll
        for (int off = 32; off > 0; off >>= 1) part += __shfl_down(part, off);
        if ((tid & 63) == 0 && part != 0) atomicAdd(&pbb[0], part);

        int cnt = A.bcur[b];
        const unsigned int* p = A.bdata + (size_t)b * A.cap;
        for (int e = tid; e < cnt; e += 256) atomicAdd(&cnts[p[e] >> 24], 1);
        __syncthreads();

        int v = cnts[tid];
        sc[tid] = v;
        __syncthreads();
        for (int off = 1; off < 256; off <<= 1) {
            int t = (tid >= off) ? sc[tid - off] : 0;
            __syncthreads();
            sc[tid] += t;
            __syncthreads();
        }
        int gstart = pbb[0] + (sc[tid] - v);
        int node = b * 256 + tid;
        if (node < A.N) {
            A.dinv[node] = rsqrtf((float)(v + 1));
            A.rowptr[node] = gstart;
        }
        cur[tid] = gstart;
        __syncthreads();

        for (int e = tid; e < cnt; e += 256) {
            unsigned int u = p[e];
            int pos = atomicAdd(&cur[u >> 24], 1);
            A.csr[pos] = (int)(u & 0xFFFFFFu);
        }
    }
}

// ---------------- MFMA GEMM phase ----------------
// block 256 = 4 waves; tile 64 rows x 128 cols; wave w: rows w*16..+15.
// in_bf16: A-fragments read from packed-bf16 global rows [row][64 uint].
// out_mode 1: packed-bf16 rows scaled by oscale[row] if given (dinv prescale).
// out_mode 2: +bias, softmax over first KOUT cols, f32 [nrows, KOUT] output.
__device__ void gemm_phase(const void* Xin, const unsigned short* Wf,
                           const float* bias, const float* oscale,
                           void* Y, int nrows, int in_bf16, int out_mode,
                           float* lds_f, int ntiles) {
    unsigned short* lds_h = (unsigned short*)lds_f;
    unsigned int* lds_u = (unsigned int*)lds_f;

    int tid = threadIdx.x;
    int w = tid >> 6, lane = tid & 63;
    int quad = lane >> 4, m16 = lane & 15;

    for (int t = blockIdx.x; t < ntiles; t += gridDim.x) {
        int r0 = t * 64;

        if (!in_bf16) {
            int row = tid >> 2, cg_ = tid & 3;
            bool valid = (r0 + row) < nrows;
            const float4* Xr = (const float4*)Xin + (size_t)(r0 + row) * 32 + cg_ * 8;
#pragma unroll
            for (int j = 0; j < 8; j++) {
                float4 v = valid ? Xr[j] : make_float4(0.f, 0.f, 0.f, 0.f);
                int c = cg_ * 32 + j * 4;
                lds_u[row * 68 + (c >> 1)]     = pack_bf(v.x, v.y);
                lds_u[row * 68 + (c >> 1) + 1] = pack_bf(v.z, v.w);
            }
            __syncthreads();
        }

        floatx4 acc[8];
#pragma unroll
        for (int ct = 0; ct < 8; ct++) acc[ct] = (floatx4){0.f, 0.f, 0.f, 0.f};

        int arow = r0 + w * 16 + m16;
        if (arow > nrows - 1) arow = nrows - 1;
        const unsigned int* Xb = (const unsigned int*)Xin;

        const short8* Wf8 = (const short8*)Wf;
#pragma unroll
        for (int kt = 0; kt < 4; kt++) {
            short8 a;
            if (in_bf16) {
                a = *(const short8*)(Xb + (size_t)arow * 64 + kt * 16 + quad * 4);
            } else {
                a = *(const short8*)(lds_h + (w * 16 + m16) * 136 + kt * 32 + quad * 8);
            }
#pragma unroll
            for (int ct = 0; ct < 8; ct++) {
                short8 b = Wf8[(kt * 8 + ct) * 64 + lane];
                acc[ct] = __builtin_amdgcn_mfma_f32_16x16x32_bf16(a, b, acc[ct], 0, 0, 0);
            }
        }

        if (out_mode == 1) {
            __syncthreads();   // reuse LDS as f32 out staging [64][130]
#pragma unroll
            for (int ct = 0; ct < 8; ct++) {
#pragma unroll
                for (int r = 0; r < 4; r++) {
                    int rl = w * 16 + quad * 4 + r;
                    lds_f[rl * 130 + ct * 16 + m16] = acc[ct][r];
                }
            }
            __syncthreads();
            unsigned int* Yb = (unsigned int*)Y;
            for (int r = 0; r < 16; r++) {
                int row = r0 + w * 16 + r;
                if (row < nrows) {
                    float sc = oscale ? oscale[row] : 1.f;
                    float lo = lds_f[(w * 16 + r) * 130 + 2 * lane] * sc;
                    float hi = lds_f[(w * 16 + r) * 130 + 2 * lane + 1] * sc;
                    Yb[(size_t)row * 64 + lane] = pack_bf(lo, hi);
                }
            }
        } else {
            float bb[8];
#pragma unroll
            for (int ct = 0; ct < 8; ct++) bb[ct] = bias[ct * 16 + m16];
            float* Yf = (float*)Y;
#pragma unroll
            for (int r = 0; r < 4; r++) {
                int row = r0 + w * 16 + quad * 4 + r;
                float vv[8];
                float mx = -1e30f;
#pragma unroll
                for (int ct = 0; ct < 8; ct++) {
                    int col = ct * 16 + m16;
                    vv[ct] = (col < KOUT) ? acc[ct][r] + bb[ct] : -1e30f;
                    mx = fmaxf(mx, vv[ct]);
                }
#pragma unroll
                for (int off = 1; off < 16; off <<= 1) mx = fmaxf(mx, __shfl_xor(mx, off));
                float se = 0.f;
#pragma unroll
                for (int ct = 0; ct < 8; ct++) {
                    vv[ct] = (vv[ct] > -1e29f) ? __expf(vv[ct] - mx) : 0.f;
                    se += vv[ct];
                }
#pragma unroll
                for (int off = 1; off < 16; off <<= 1) se += __shfl_xor(se, off);
                float inv = 1.f / se;
                if (row < nrows) {
#pragma unroll
                    for (int ct = 0; ct < 8; ct++) {
                        int col = ct * 16 + m16;
                        if (col < KOUT) Yf[(size_t)row * KOUT + col] = vv[ct] * inv;
                    }
                }
            }
        }
        __syncthreads();   // protect LDS reuse across tile iterations
    }
}

// ---------------- Aggregate phase (r0 structure: 256 B rows, un-chunked) ----------
// wave per node (grid-strided); 4 groups of 16 lanes, group = 1 edge slot,
// lane = uint4 (8 feats). dinv recomputed as rsqrtf(cnt+1) (== bucket_build).
// Next node's rowptr prefetched before the gather loop to hide its latency.
__device__ void agg_phase(const unsigned int* __restrict__ Hb, const int* __restrict__ csr,
                          const int* __restrict__ rowptr, const float* __restrict__ bias,
                          unsigned int* __restrict__ Ob, int n, int do_relu) {
    int wid = threadIdx.x >> 6, lane = threadIdx.x & 63;
    int g = lane >> 4, c = lane & 15;
    int wgid = blockIdx.x * 4 + wid;
    int wstride = gridDim.x * 4;
    const char* Tb = (const char*)Hb;
    unsigned coff = (unsigned)c * 16u;

    int i = wgid;
    int start = 0, cnt = 0;
    if (i < n) { start = rowptr[i]; cnt = rowptr[i + 1] - start; }

    while (i < n) {
        int inext = i + wstride;
        int nstart = 0, ncnt = 0;
        if (inext < n) { nstart = rowptr[inext]; ncnt = rowptr[inext + 1] - nstart; }

        const int* cp = csr + start;
        float di = rsqrtf((float)(cnt + 1));

        float acc[8];
        {   // self term (group 0 only); rows are dinv[src]-prescaled by the GEMM
            uintx4 sv = (uintx4){0u, 0u, 0u, 0u};
            if (g == 0) sv = *(const uintx4*)(Tb + (unsigned)i * 256u + coff);
            acc[0] = bf_lo(sv.x); acc[1] = bf_hi(sv.x);
            acc[2] = bf_lo(sv.y); acc[3] = bf_hi(sv.y);
            acc[4] = bf_lo(sv.z); acc[5] = bf_hi(sv.z);
            acc[6] = bf_lo(sv.w); acc[7] = bf_hi(sv.w);
        }

        int s[4];
#pragma unroll
        for (int u = 0; u < 4; u++) {
            int idx = u * 4 + g;
            s[u] = (idx < cnt) ? cp[idx] : n;          // n = zero row
        }
        for (int e = 0; e < cnt; e += 16) {
            uintx4 v[4];
#pragma unroll
            for (int u = 0; u < 4; u++)
                v[u] = *(const uintx4*)(Tb + (unsigned)s[u] * 256u + coff);
            int ns[4];
#pragma unroll
            for (int u = 0; u < 4; u++) {
                int idx = e + 16 + u * 4 + g;
                ns[u] = (idx < cnt) ? cp[idx] : n;
            }
#pragma unroll
            for (int u = 0; u < 4; u++) {
                acc[0] += bf_lo(v[u].x); acc[1] += bf_hi(v[u].x);
                acc[2] += bf_lo(v[u].y); acc[3] += bf_hi(v[u].y);
                acc[4] += bf_lo(v[u].z); acc[5] += bf_hi(v[u].z);
                acc[6] += bf_lo(v[u].w); acc[7] += bf_hi(v[u].w);
            }
#pragma unroll
            for (int u = 0; u < 4; u++) s[u] = ns[u];
        }

        // butterfly across the 4 groups (lane bits 4,5)
#pragma unroll
        for (int j = 0; j < 8; j++) {
            acc[j] += __shfl_xor(acc[j], 16);
            acc[j] += __shfl_xor(acc[j], 32);
        }

        // lane (g,c) writes feature pair p = c*4+g
        float2 bb = ((const float2*)bias)[c * 4 + g];
        float fx = acc[g * 2]     * di + bb.x;
        float fy = acc[g * 2 + 1] * di + bb.y;
        if (do_relu) { fx = fmaxf(fx, 0.f); fy = fmaxf(fy, 0.f); }
        Ob[(size_t)i * 64 + c * 4 + g] = pack_bf(fx, fy);

        i = inext; start = nstart; cnt = ncnt;
    }
}

// ---------------- cooperative mega-kernel: whole pipeline, 1 launch ----------------
__launch_bounds__(256, 4)
__global__ void mega_kernel(MegaArgs A) {
    __shared__ float lds_f[64 * 130];          // 33280 B (union for all phases)
    cg::grid_group grid = cg::this_grid();

    prep_body(A);
    grid.sync();
    pass1_phase(A, lds_f);
    grid.sync();
    build_phase(A, lds_f);
    grid.sync();
    gemm_phase(A.x, A.Wf1, nullptr, A.dinv, A.HbA, A.N, 0, 1, lds_f, A.nbGemm);
    grid.sync();
    agg_phase(A.HbA, A.csr, A.rowptr, A.b1, A.HbB, A.N, 1);
    grid.sync();
    gemm_phase(A.HbB, A.Wf2, nullptr, A.dinv, A.HbA, A.N, 1, 1, lds_f, A.nbGemm);
    grid.sync();
    agg_phase(A.HbA, A.csr, A.rowptr, A.b2, A.HbB, A.N, 0);
    grid.sync();
    gemm_phase(A.HbB, A.WfA, A.bpad, nullptr, A.out, A.N, 1, 2, lds_f, A.nbGemm);
}

// ---------------- fallback wrappers (if cooperative launch unavailable) ----------
__launch_bounds__(256) __global__ void k_prep(MegaArgs A) { prep_body(A); }
__launch_bounds__(256) __global__ void k_pass1(MegaArgs A) {
    __shared__ float lds[64 * 130]; pass1_phase(A, lds);
}
__launch_bounds__(256) __global__ void k_build(MegaArgs A) {
    __shared__ float lds[64 * 130]; build_phase(A, lds);
}
__launch_bounds__(256) __global__ void k_gemm(const void* Xin, const unsigned short* Wf,
                                              const float* bias, const float* oscale,
                                              void* Y, int nrows, int in_bf16, int out_mode,
                                              int ntiles) {
    __shared__ float lds[64 * 130];
    gemm_phase(Xin, Wf, bias, oscale, Y, nrows, in_bf16, out_mode, lds, ntiles);
}
__launch_bounds__(256) __global__ void k_agg(const unsigned int* Hb, const int* csr,
                                             const int* rowptr, const float* bias,
                                             unsigned int* Ob, int n, int do_relu) {
    agg_phase(Hb, csr, rowptr, bias, Ob, n, do_relu);
}

// ---------------- launch ----------------
extern "C" void kernel_launch(void* const* d_in, const int* in_sizes, int n_in,
                              void* d_out, int out_size, void* d_ws, size_t ws_size,
                              hipStream_t stream) {
    const float* x  = (const float*)d_in[0];
    const int*   ei = (const int*)d_in[1];     // [2,E] int32
    const float* W1 = (const float*)d_in[2];
    const float* b1 = (const float*)d_in[3];
    const float* W2 = (const float*)d_in[4];
    const float* b2 = (const float*)d_in[5];
    const float* Wa = (const float*)d_in[6];
    const float* ba = (const float*)d_in[7];
    float* out = (float*)d_out;

    int N = in_sizes[0] / D;
    int E = in_sizes[1] / 2;

    int nbuck = (N + 255) >> 8;                       // 196 for N=50000
    int cap = ((E / nbuck) + 2048 + 63) & ~63;

    char* w = (char*)d_ws;
    size_t off = 0;
    auto carve = [&](size_t bytes) -> void* {
        void* p = w + off;
        off = (off + bytes + 255) & ~(size_t)255;
        return p;
    };
    float* dinv   = (float*)carve((size_t)N * 4);
    int*   rowptr = (int*)carve((size_t)(N + 1) * 4);
    int*   bcur   = (int*)carve(256 * 4);
    unsigned int* bdata = (unsigned int*)carve((size_t)nbuck * cap * 4);
    int*   csr    = (int*)carve((size_t)E * 4);
    unsigned short* Wf1 = (unsigned short*)carve(16384 * 2);
    unsigned short* Wf2 = (unsigned short*)carve(16384 * 2);
    unsigned short* WfA = (unsigned short*)carve(16384 * 2);
    float* bpad   = (float*)carve(512);
    unsigned int* HbA = (unsigned int*)carve((size_t)(N + 1) * 64 * 4);  // +1 zero row
    unsigned int* HbB = (unsigned int*)carve((size_t)(N + 1) * 64 * 4);
    (void)ws_size; (void)n_in; (void)out_size;

    MegaArgs a;
    a.x = x; a.ei = ei; a.W1 = W1; a.b1 = b1; a.W2 = W2; a.b2 = b2;
    a.Wa = Wa; a.ba = ba; a.out = out;
    a.dinv = dinv; a.rowptr = rowptr; a.bcur = bcur; a.bdata = bdata; a.csr = csr;
    a.Wf1 = Wf1; a.Wf2 = Wf2; a.WfA = WfA; a.bpad = bpad;
    a.HbA = HbA; a.HbB = HbB;
    a.N = N; a.E = E; a.nbuck = nbuck; a.cap = cap;
    a.nbP1 = (E + CHUNK - 1) / CHUNK;
    a.nbGemm = (N + 63) / 64;

    // co-resident grid: LDS 33.3 KB + launch_bounds(256,4) -> 4 blocks/CU x 256 CUs
    int occ = 0;
    hipError_t oe = hipOccupancyMaxActiveBlocksPerMultiprocessor(
        &occ, (const void*)mega_kernel, 256, 0);
    if (oe != hipSuccess || occ < 1) occ = 1;
    int grid = occ * 256;
    if (grid > 1024) grid = 1024;

    void* kp[] = { (void*)&a };
    hipError_t err = hipLaunchCooperativeKernel((const void*)mega_kernel,
                                                dim3(grid), dim3(256), kp, 0, stream);
    if (err != hipSuccess) {
        // fallback: classic multi-launch pipeline (same device code)
        int nbNode4 = (N + 3) / 4;
        k_prep<<<192, 256, 0, stream>>>(a);
        k_pass1<<<a.nbP1, 256, 0, stream>>>(a);
        k_build<<<nbuck, 256, 0, stream>>>(a);
        k_gemm<<<a.nbGemm, 256, 0, stream>>>(x, Wf1, nullptr, dinv, HbA, N, 0, 1, a.nbGemm);
        k_agg<<<nbNode4, 256, 0, stream>>>(HbA, csr, rowptr, b1, HbB, N, 1);
        k_gemm<<<a.nbGemm, 256, 0, stream>>>(HbB, Wf2, nullptr, dinv, HbA, N, 1, 1, a.nbGemm);
        k_agg<<<nbNode4, 256, 0, stream>>>(HbA, csr, rowptr, b2, HbB, N, 0);
        k_gemm<<<a.nbGemm, 256, 0, stream>>>(HbB, WfA, bpad, nullptr, out, N, 1, 2, a.nbGemm);
    }
}

// Round 6
// 273.810 us; speedup vs baseline: 2.3469x; 2.3469x over previous
//
#include <hip/hip_runtime.h>

#define D 128
#define KOUT 100
#define CHUNK 4096   // edges per pass-1 block

typedef __attribute__((ext_vector_type(8))) short short8;
typedef __attribute__((ext_vector_type(4))) float floatx4;
typedef __attribute__((ext_vector_type(4))) unsigned int uintx4;

// ---------------- bf16 pack/unpack helpers ----------------
__device__ inline float bf_lo(unsigned int u) { return __uint_as_float(u << 16); }
__device__ inline float bf_hi(unsigned int u) { return __uint_as_float(u & 0xFFFF0000u); }

__device__ inline unsigned int bf_round(float a) {      // f32 -> bf16 bits (RNE)
    unsigned int ua = __float_as_uint(a);
    return (ua + 0x7FFFu + ((ua >> 16) & 1u)) >> 16;
}
__device__ inline unsigned int pack_bf(float a, float b) {
    return bf_round(a) | (bf_round(b) << 16);
}

// ---------------- CSR build pass 1: bucket radix partition ----------------
// bucket = dst >> 8; packed record: bits[23:0]=src, bits[31:24]=dst&255

__launch_bounds__(256)
__global__ void bucket_pass1(const int* __restrict__ ei, int E, int nbuck, int cap,
                             int* __restrict__ bcur, unsigned int* __restrict__ bdata) {
    __shared__ int hist[256];
    __shared__ int sc[256];
    __shared__ int pfx[256];
    __shared__ int cur[256];
    __shared__ int gbase[256];
    __shared__ unsigned int lbuf[CHUNK];      // 16 KB
    __shared__ unsigned char bkt[CHUNK];      // 4 KB

    int tid = threadIdx.x;
    int base = blockIdx.x * CHUNK;
    int cnt = E - base; if (cnt > CHUNK) cnt = CHUNK;

    hist[tid] = 0;
    __syncthreads();

    int src[CHUNK / 256];
    int dst[CHUNK / 256];
#pragma unroll
    for (int q = 0; q < CHUNK / 256; q++) {
        int li = tid + q * 256;
        if (li < cnt) {
            src[q] = ei[base + li];
            dst[q] = ei[E + base + li];
            atomicAdd(&hist[dst[q] >> 8], 1);
        }
    }
    __syncthreads();

    int v = hist[tid];
    sc[tid] = v;
    __syncthreads();
    for (int off = 1; off < 256; off <<= 1) {
        int t = (tid >= off) ? sc[tid - off] : 0;
        __syncthreads();
        sc[tid] += t;
        __syncthreads();
    }
    int excl = sc[tid] - v;
    pfx[tid] = excl;
    cur[tid] = excl;
    gbase[tid] = 0;
    if (tid < nbuck && v > 0) gbase[tid] = atomicAdd(&bcur[tid], v);
    __syncthreads();

#pragma unroll
    for (int q = 0; q < CHUNK / 256; q++) {
        int li = tid + q * 256;
        if (li < cnt) {
            int b = dst[q] >> 8;
            int p = atomicAdd(&cur[b], 1);
            lbuf[p] = (unsigned int)src[q] | ((unsigned int)(dst[q] & 255) << 24);
            bkt[p] = (unsigned char)b;
        }
    }
    __syncthreads();

    for (int p = tid; p < cnt; p += 256) {
        int b = bkt[p];
        bdata[(size_t)b * cap + gbase[b] + (p - pfx[b])] = lbuf[p];
    }
}

// ---------------- CSR build pass 2 (fused): dinv + rowptr + scatter ----------------
// one block per bucket; bdata read twice (2nd read L2-hot).

__launch_bounds__(256)
__global__ void bucket_build(const unsigned int* __restrict__ bdata, const int* __restrict__ bcur,
                             int cap, float* __restrict__ dinv,
                             int* __restrict__ rowptr, int* __restrict__ csr, int n, int nbuck) {
    __shared__ int cnts[256];
    __shared__ int sc[256];
    __shared__ int cur[256];
    __shared__ int bbase;

    int b = blockIdx.x, tid = threadIdx.x;
    if (tid == 0) bbase = 0;
    cnts[tid] = 0;
    __syncthreads();

    // sum of bucket counts before b
    int part = 0;
    for (int t = tid; t < b; t += 256) part += bcur[t];
#pragma unroll
    for (int off = 32; off > 0; off >>= 1) part += __shfl_down(part, off);
    if ((tid & 63) == 0 && part != 0) atomicAdd(&bbase, part);

    int cnt = bcur[b];
    const unsigned int* p = bdata + (size_t)b * cap;
    for (int e = tid; e < cnt; e += 256) atomicAdd(&cnts[p[e] >> 24], 1);
    __syncthreads();

    int v = cnts[tid];
    sc[tid] = v;
    __syncthreads();
    for (int off = 1; off < 256; off <<= 1) {
        int t = (tid >= off) ? sc[tid - off] : 0;
        __syncthreads();
        sc[tid] += t;
        __syncthreads();
    }
    int gstart = bbase + (sc[tid] - v);
    int node = b * 256 + tid;
    if (node < n) {
        dinv[node] = rsqrtf((float)(v + 1));
        rowptr[node] = gstart;
    }
    cur[tid] = gstart;
    __syncthreads();

    for (int e = tid; e < cnt; e += 256) {
        unsigned int u = p[e];
        int pos = atomicAdd(&cur[u >> 24], 1);
        csr[pos] = (int)(u & 0xFFFFFFu);
    }
}

// ---------------- Weight prep + bcur zero + Hb zero-rows + rowptr sentinel ----------------
// Wfrag[(kt*8+ct)*64 + lane][j] = W[kt*32 + (lane>>4)*8 + j][ct*16 + (lane&15)]

__global__ void prep_frag_kernel(const float* __restrict__ W1, const float* __restrict__ W2,
                                 const float* __restrict__ Wa, const float* __restrict__ ba,
                                 unsigned short* __restrict__ Wf1, unsigned short* __restrict__ Wf2,
                                 unsigned short* __restrict__ WfA, float* __restrict__ bpad,
                                 int* __restrict__ bcur, int* __restrict__ rowptr,
                                 unsigned int* __restrict__ zrowA, unsigned int* __restrict__ zrowB,
                                 int n, int E) {
    int idx = blockIdx.x * blockDim.x + threadIdx.x;
    if (idx < 3 * 16384) {
        int m = idx / 16384;
        int e = idx & 16383;
        int j = e & 7, lane = (e >> 3) & 63, ct = (e >> 9) & 7, kt = e >> 12;
        int k = kt * 32 + (lane >> 4) * 8 + j;
        int col = ct * 16 + (lane & 15);
        float val;
        unsigned short* dst;
        if (m == 0)      { val = W1[k * 128 + col]; dst = Wf1; }
        else if (m == 1) { val = W2[k * 128 + col]; dst = Wf2; }
        else             { val = (col < KOUT) ? Wa[k * KOUT + col] : 0.f; dst = WfA; }
        dst[e] = (unsigned short)bf_round(val);
    }
    if (idx < 128) bpad[idx] = (idx < KOUT) ? ba[idx] : 0.f;
    if (idx < 256) bcur[idx] = 0;
    if (idx < 64) { zrowA[idx] = 0u; zrowB[idx] = 0u; }
    if (idx == 256) rowptr[n] = E;   // sentinel
}

// ---------------- MFMA GEMM ----------------
// block 256 = 4 waves; tile 64 rows x 128 cols; wave w: rows w*16..+15.
// in_bf16: A-fragments read directly from packed-bf16 global rows.
// out_mode 1: packed-bf16 rows, each row scaled by oscale[row] if given (dinv prescale).
// out_mode 2: +bias, softmax over first KOUT cols, f32 [nrows, KOUT] output.

__launch_bounds__(256)
__global__ void gemm_mfma_kernel(const void* __restrict__ Xin, const unsigned short* __restrict__ Wf,
                                 const float* __restrict__ bias, const float* __restrict__ oscale,
                                 void* __restrict__ Y, int nrows, int in_bf16, int out_mode) {
    __shared__ float lds_f[64 * 130];                      // 33280 B
    unsigned short* lds_h = (unsigned short*)lds_f;
    unsigned int* lds_u = (unsigned int*)lds_f;

    int tid = threadIdx.x;
    int w = tid >> 6, lane = tid & 63;
    int quad = lane >> 4, m16 = lane & 15;
    int r0 = blockIdx.x * 64;

    if (!in_bf16) {
        int row = tid >> 2, cg_ = tid & 3;
        bool valid = (r0 + row) < nrows;
        const float4* Xr = (const float4*)Xin + (size_t)(r0 + row) * 32 + cg_ * 8;
#pragma unroll
        for (int j = 0; j < 8; j++) {
            float4 v = valid ? Xr[j] : make_float4(0.f, 0.f, 0.f, 0.f);
            int c = cg_ * 32 + j * 4;
            lds_u[row * 68 + (c >> 1)]     = pack_bf(v.x, v.y);
            lds_u[row * 68 + (c >> 1) + 1] = pack_bf(v.z, v.w);
        }
        __syncthreads();
    }

    floatx4 acc[8];
#pragma unroll
    for (int ct = 0; ct < 8; ct++) acc[ct] = (floatx4){0.f, 0.f, 0.f, 0.f};

    int arow = r0 + w * 16 + m16;
    if (arow > nrows - 1) arow = nrows - 1;
    const unsigned int* Xb = (const unsigned int*)Xin;

    const short8* Wf8 = (const short8*)Wf;
#pragma unroll
    for (int kt = 0; kt < 4; kt++) {
        short8 a;
        if (in_bf16) {
            a = *(const short8*)(Xb + (size_t)arow * 64 + kt * 16 + quad * 4);
        } else {
            a = *(const short8*)(lds_h + (w * 16 + m16) * 136 + kt * 32 + quad * 8);
        }
#pragma unroll
        for (int ct = 0; ct < 8; ct++) {
            short8 b = Wf8[(kt * 8 + ct) * 64 + lane];
            acc[ct] = __builtin_amdgcn_mfma_f32_16x16x32_bf16(a, b, acc[ct], 0, 0, 0);
        }
    }

    if (out_mode == 1) {
        __syncthreads();   // reuse LDS as f32 out staging [64][130]
#pragma unroll
        for (int ct = 0; ct < 8; ct++) {
#pragma unroll
            for (int r = 0; r < 4; r++) {
                int rl = w * 16 + quad * 4 + r;
                lds_f[rl * 130 + ct * 16 + m16] = acc[ct][r];
            }
        }
        __syncthreads();
        unsigned int* Yb = (unsigned int*)Y;
        for (int r = 0; r < 16; r++) {
            int row = r0 + w * 16 + r;
            if (row < nrows) {
                float sc = oscale ? oscale[row] : 1.f;
                float lo = lds_f[(w * 16 + r) * 130 + 2 * lane] * sc;
                float hi = lds_f[(w * 16 + r) * 130 + 2 * lane + 1] * sc;
                Yb[(size_t)row * 64 + lane] = pack_bf(lo, hi);
            }
        }
    } else {
        // out_mode 2: bias + softmax over cols < KOUT, f32 output [nrows, KOUT]
        float bb[8];
#pragma unroll
        for (int ct = 0; ct < 8; ct++) bb[ct] = bias[ct * 16 + m16];
        float* Yf = (float*)Y;
#pragma unroll
        for (int r = 0; r < 4; r++) {
            int row = r0 + w * 16 + quad * 4 + r;
            float vv[8];
            float mx = -1e30f;
#pragma unroll
            for (int ct = 0; ct < 8; ct++) {
                int col = ct * 16 + m16;
                vv[ct] = (col < KOUT) ? acc[ct][r] + bb[ct] : -1e30f;
                mx = fmaxf(mx, vv[ct]);
            }
#pragma unroll
            for (int off = 1; off < 16; off <<= 1) mx = fmaxf(mx, __shfl_xor(mx, off));
            float se = 0.f;
#pragma unroll
            for (int ct = 0; ct < 8; ct++) {
                vv[ct] = (vv[ct] > -1e29f) ? __expf(vv[ct] - mx) : 0.f;
                se += vv[ct];
            }
#pragma unroll
            for (int off = 1; off < 16; off <<= 1) se += __shfl_xor(se, off);
            float inv = 1.f / se;
            if (row < nrows) {
#pragma unroll
                for (int ct = 0; ct < 8; ct++) {
                    int col = ct * 16 + m16;
                    if (col < KOUT) Yf[(size_t)row * KOUT + col] = vv[ct] * inv;
                }
            }
        }
    }
}

// ---------------- Aggregate (r0 structure, 8-deep in-flight) ----------------
// Ob[i] = bf16( di*(Σ Hb'[src] + Hb'[i]) + b ); rows dinv[src]-prescaled by GEMM.
// one wave per node; 4 groups of 16 lanes, group = 1 edge slot, lane = uint4.
// Unroll-2: 8 independent 1 KB row-gathers in flight per wave (8 KB) -> 2x
// latency depth vs r0 (which was latency-bound: L2 5.9/34.5 TB/s, beyond-L2
// 3.3 TB/s, VALU 50% -- nothing saturated). csr loads nontemporal (read-once,
// keeps table lines in L2). dinv recomputed as rsqrtf(cnt+1) (== bucket_build
// bit-exact) to drop a dependent load. 32-bit row addressing.
// masked tail points at zero-row index n (rowptr[n]=E sentinel gives cnt).

__launch_bounds__(256)
__global__ void aggregate_kernel(const unsigned int* __restrict__ Hb, const int* __restrict__ csr,
                                 const int* __restrict__ rowptr,
                                 const float* __restrict__ bias,
                                 unsigned int* __restrict__ Ob, int n, int do_relu) {
    int wid = threadIdx.x >> 6, lane = threadIdx.x & 63;
    int g = lane >> 4, c = lane & 15;
    int i = blockIdx.x * 4 + wid;
    if (i >= n) return;

    int start = rowptr[i];
    int cnt = rowptr[i + 1] - start;
    const int* cp = csr + start;
    float di = rsqrtf((float)(cnt + 1));          // == dinv[i] (same formula as build)

    const char* Tb = (const char*)Hb;
    unsigned coff = (unsigned)c * 16u;

    float acc[8];
    {   // self term (group 0 only)
        uintx4 sv = (uintx4){0u, 0u, 0u, 0u};
        if (g == 0) sv = *(const uintx4*)(Tb + (unsigned)i * 256u + coff);
        acc[0] = bf_lo(sv.x); acc[1] = bf_hi(sv.x);
        acc[2] = bf_lo(sv.y); acc[3] = bf_hi(sv.y);
        acc[4] = bf_lo(sv.z); acc[5] = bf_hi(sv.z);
        acc[6] = bf_lo(sv.w); acc[7] = bf_hi(sv.w);
    }

    int s[8];
#pragma unroll
    for (int u = 0; u < 8; u++) {
        int idx = u * 4 + g;
        s[u] = (idx < cnt) ? __builtin_nontemporal_load(cp + idx) : n;   // n = zero row
    }
    for (int e = 0; e < cnt; e += 32) {
        uintx4 v[8];
#pragma unroll
        for (int u = 0; u < 8; u++)
            v[u] = *(const uintx4*)(Tb + (unsigned)s[u] * 256u + coff);
        int ns[8];
#pragma unroll
        for (int u = 0; u < 8; u++) {
            int idx = e + 32 + u * 4 + g;
            ns[u] = (idx < cnt) ? __builtin_nontemporal_load(cp + idx) : n;
        }
#pragma unroll
        for (int u = 0; u < 8; u++) {
            acc[0] += bf_lo(v[u].x); acc[1] += bf_hi(v[u].x);
            acc[2] += bf_lo(v[u].y); acc[3] += bf_hi(v[u].y);
            acc[4] += bf_lo(v[u].z); acc[5] += bf_hi(v[u].z);
            acc[6] += bf_lo(v[u].w); acc[7] += bf_hi(v[u].w);
        }
#pragma unroll
        for (int u = 0; u < 8; u++) s[u] = ns[u];
    }

    // butterfly across the 4 groups (lane bits 4,5)
#pragma unroll
    for (int j = 0; j < 8; j++) {
        acc[j] += __shfl_xor(acc[j], 16);
        acc[j] += __shfl_xor(acc[j], 32);
    }

    // lane (g,c) writes feature pair p = c*4+g (feats 8c+2g, 8c+2g+1)
    float2 bb = ((const float2*)bias)[c * 4 + g];
    float fx = acc[g * 2]     * di + bb.x;
    float fy = acc[g * 2 + 1] * di + bb.y;
    if (do_relu) { fx = fmaxf(fx, 0.f); fy = fmaxf(fy, 0.f); }
    Ob[(size_t)i * 64 + c * 4 + g] = pack_bf(fx, fy);
}

// ---------------- launch ----------------

extern "C" void kernel_launch(void* const* d_in, const int* in_sizes, int n_in,
                              void* d_out, int out_size, void* d_ws, size_t ws_size,
                              hipStream_t stream) {
    const float* x  = (const float*)d_in[0];
    const int*   ei = (const int*)d_in[1];     // [2,E] int32
    const float* W1 = (const float*)d_in[2];
    const float* b1 = (const float*)d_in[3];
    const float* W2 = (const float*)d_in[4];
    const float* b2 = (const float*)d_in[5];
    const float* Wa = (const float*)d_in[6];
    const float* ba = (const float*)d_in[7];
    float* out = (float*)d_out;

    int N = in_sizes[0] / D;
    int E = in_sizes[1] / 2;

    int nbuck = (N + 255) >> 8;                       // 196 for N=50000
    int cap = ((E / nbuck) + 2048 + 63) & ~63;

    char* w = (char*)d_ws;
    size_t off = 0;
    auto carve = [&](size_t bytes) -> void* {
        void* p = w + off;
        off = (off + bytes + 255) & ~(size_t)255;
        return p;
    };
    float* dinv   = (float*)carve((size_t)N * 4);
    int*   rowptr = (int*)carve((size_t)(N + 1) * 4);
    int*   bcur   = (int*)carve(256 * 4);
    unsigned int* bdata = (unsigned int*)carve((size_t)nbuck * cap * 4);
    int*   csr    = (int*)carve((size_t)E * 4);
    unsigned short* Wf1 = (unsigned short*)carve(16384 * 2);
    unsigned short* Wf2 = (unsigned short*)carve(16384 * 2);
    unsigned short* WfA = (unsigned short*)carve(16384 * 2);
    float* bpad   = (float*)carve(512);
    unsigned int* HbA = (unsigned int*)carve((size_t)(N + 1) * 64 * 4);  // +1 zero row
    unsigned int* HbB = (unsigned int*)carve((size_t)(N + 1) * 64 * 4);
    (void)ws_size; (void)n_in; (void)out_size;

    int nbNode4 = (N + 3) / 4;
    int nbGemm = (N + 63) / 64;
    int nbP1 = (E + CHUNK - 1) / CHUNK;

    prep_frag_kernel<<<192, 256, 0, stream>>>(W1, W2, Wa, ba, Wf1, Wf2, WfA, bpad,
                                              bcur, rowptr,
                                              HbA + (size_t)N * 64, HbB + (size_t)N * 64, N, E);
    bucket_pass1<<<nbP1, 256, 0, stream>>>(ei, E, nbuck, cap, bcur, bdata);
    bucket_build<<<nbuck, 256, 0, stream>>>(bdata, bcur, cap, dinv, rowptr, csr, N, nbuck);

    // layer 1 (gemm writes bf16(h*dinv) rows)
    gemm_mfma_kernel<<<nbGemm, 256, 0, stream>>>(x, Wf1, nullptr, dinv, HbA, N, 0, 1);
    aggregate_kernel<<<nbNode4, 256, 0, stream>>>(HbA, csr, rowptr, b1, HbB, N, 1);
    // layer 2
    gemm_mfma_kernel<<<nbGemm, 256, 0, stream>>>(HbB, Wf2, nullptr, dinv, HbA, N, 1, 1);
    aggregate_kernel<<<nbNode4, 256, 0, stream>>>(HbA, csr, rowptr, b2, HbB, N, 0);
    // attention + fused softmax -> out
    gemm_mfma_kernel<<<nbGemm, 256, 0, stream>>>(HbB, WfA, bpad, nullptr, out, N, 1, 2);
}

// Round 7
// 254.780 us; speedup vs baseline: 2.5222x; 1.0747x over previous
//
#include <hip/hip_runtime.h>

#define D 128
#define KOUT 100
#define CHUNK 4096   // edges per pass-1 block

typedef __attribute__((ext_vector_type(8))) short short8;
typedef __attribute__((ext_vector_type(4))) float floatx4;

// ---------------- bf16 pack/unpack helpers ----------------
__device__ inline float bf_lo(unsigned int u) { return __uint_as_float(u << 16); }
__device__ inline float bf_hi(unsigned int u) { return __uint_as_float(u & 0xFFFF0000u); }

__device__ inline unsigned int bf_round(float a) {      // f32 -> bf16 bits (RNE)
    unsigned int ua = __float_as_uint(a);
    return (ua + 0x7FFFu + ((ua >> 16) & 1u)) >> 16;
}
__device__ inline unsigned int pack_bf(float a, float b) {
    return bf_round(a) | (bf_round(b) << 16);
}

// ---------------- CSR build pass 1: bucket radix partition ----------------
// bucket = dst >> 8; packed record: bits[23:0]=src, bits[31:24]=dst&255

__launch_bounds__(256)
__global__ void bucket_pass1(const int* __restrict__ ei, int E, int nbuck, int cap,
                             int* __restrict__ bcur, unsigned int* __restrict__ bdata) {
    __shared__ int hist[256];
    __shared__ int sc[256];
    __shared__ int pfx[256];
    __shared__ int cur[256];
    __shared__ int gbase[256];
    __shared__ unsigned int lbuf[CHUNK];      // 16 KB
    __shared__ unsigned char bkt[CHUNK];      // 4 KB

    int tid = threadIdx.x;
    int base = blockIdx.x * CHUNK;
    int cnt = E - base; if (cnt > CHUNK) cnt = CHUNK;

    hist[tid] = 0;
    __syncthreads();

    int src[CHUNK / 256];
    int dst[CHUNK / 256];
#pragma unroll
    for (int q = 0; q < CHUNK / 256; q++) {
        int li = tid + q * 256;
        if (li < cnt) {
            src[q] = ei[base + li];
            dst[q] = ei[E + base + li];
            atomicAdd(&hist[dst[q] >> 8], 1);
        }
    }
    __syncthreads();

    int v = hist[tid];
    sc[tid] = v;
    __syncthreads();
    for (int off = 1; off < 256; off <<= 1) {
        int t = (tid >= off) ? sc[tid - off] : 0;
        __syncthreads();
        sc[tid] += t;
        __syncthreads();
    }
    int excl = sc[tid] - v;
    pfx[tid] = excl;
    cur[tid] = excl;
    gbase[tid] = 0;
    if (tid < nbuck && v > 0) gbase[tid] = atomicAdd(&bcur[tid], v);
    __syncthreads();

#pragma unroll
    for (int q = 0; q < CHUNK / 256; q++) {
        int li = tid + q * 256;
        if (li < cnt) {
            int b = dst[q] >> 8;
            int p = atomicAdd(&cur[b], 1);
            lbuf[p] = (unsigned int)src[q] | ((unsigned int)(dst[q] & 255) << 24);
            bkt[p] = (unsigned char)b;
        }
    }
    __syncthreads();

    for (int p = tid; p < cnt; p += 256) {
        int b = bkt[p];
        bdata[(size_t)b * cap + gbase[b] + (p - pfx[b])] = lbuf[p];
    }
}

// ---------------- CSR build pass 2 (fused): dinv + rowptr + scatter ----------------
// one block per bucket; bdata read twice (2nd read L2-hot).

__launch_bounds__(256)
__global__ void bucket_build(const unsigned int* __restrict__ bdata, const int* __restrict__ bcur,
                             int cap, float* __restrict__ dinv,
                             int* __restrict__ rowptr, int* __restrict__ csr, int n, int nbuck) {
    __shared__ int cnts[256];
    __shared__ int sc[256];
    __shared__ int cur[256];
    __shared__ int bbase;

    int b = blockIdx.x, tid = threadIdx.x;
    if (tid == 0) bbase = 0;
    cnts[tid] = 0;
    __syncthreads();

    // sum of bucket counts before b
    int part = 0;
    for (int t = tid; t < b; t += 256) part += bcur[t];
#pragma unroll
    for (int off = 32; off > 0; off >>= 1) part += __shfl_down(part, off);
    if ((tid & 63) == 0 && part != 0) atomicAdd(&bbase, part);

    int cnt = bcur[b];
    const unsigned int* p = bdata + (size_t)b * cap;
    for (int e = tid; e < cnt; e += 256) atomicAdd(&cnts[p[e] >> 24], 1);
    __syncthreads();

    int v = cnts[tid];
    sc[tid] = v;
    __syncthreads();
    for (int off = 1; off < 256; off <<= 1) {
        int t = (tid >= off) ? sc[tid - off] : 0;
        __syncthreads();
        sc[tid] += t;
        __syncthreads();
    }
    int gstart = bbase + (sc[tid] - v);
    int node = b * 256 + tid;
    if (node < n) {
        dinv[node] = rsqrtf((float)(v + 1));
        rowptr[node] = gstart;
    }
    cur[tid] = gstart;
    __syncthreads();

    for (int e = tid; e < cnt; e += 256) {
        unsigned int u = p[e];
        int pos = atomicAdd(&cur[u >> 24], 1);
        csr[pos] = (int)(u & 0xFFFFFFu);
    }
}

// ---------------- Weight prep (incl. fused W2*Wa) + bcur zero + zero-rows + sentinel ----
// Wfrag[(kt*8+ct)*64 + lane][j] = W[kt*32 + (lane>>4)*8 + j][ct*16 + (lane&15)]
// Layer-2 algebraic fusion: agg commutes with right-mult, no relu between
// agg2 and the attention GEMM, so  out = softmax((A.h1).(W2.Wa) + (b2.Wa + ba)).
// WfF = bf16-fragments of W2@Wa (128x100, padded); bpad = b2@Wa + ba (padded).

__global__ void prep_frag_kernel(const float* __restrict__ W1, const float* __restrict__ W2,
                                 const float* __restrict__ Wa, const float* __restrict__ ba,
                                 const float* __restrict__ b2,
                                 unsigned short* __restrict__ Wf1, unsigned short* __restrict__ WfF,
                                 float* __restrict__ bpad,
                                 int* __restrict__ bcur, int* __restrict__ rowptr,
                                 unsigned int* __restrict__ zrowA, unsigned int* __restrict__ zrowB,
                                 int n, int E) {
    int idx = blockIdx.x * blockDim.x + threadIdx.x;
    if (idx < 2 * 16384) {
        int m = idx >> 14;
        int e = idx & 16383;
        int j = e & 7, lane = (e >> 3) & 63, ct = (e >> 9) & 7, kt = e >> 12;
        int k = kt * 32 + (lane >> 4) * 8 + j;
        int col = ct * 16 + (lane & 15);
        if (m == 0) {
            Wf1[e] = (unsigned short)bf_round(W1[k * 128 + col]);
        } else {
            // Wfused[k][col] = sum_mm W2[k][mm] * Wa[mm][col]  (f32 accumulate)
            float s = 0.f;
            if (col < KOUT) {
                const float* w2r = W2 + k * 128;
#pragma unroll 8
                for (int mm = 0; mm < 128; mm++)
                    s = fmaf(w2r[mm], Wa[mm * KOUT + col], s);
            }
            WfF[e] = (unsigned short)bf_round(s);
        }
    }
    if (idx < 128) {
        float s = 0.f;
        if (idx < KOUT) {
            for (int mm = 0; mm < 128; mm++)
                s = fmaf(b2[mm], Wa[mm * KOUT + idx], s);
            s += ba[idx];
        }
        bpad[idx] = s;
    }
    if (idx < 256) bcur[idx] = 0;
    if (idx < 64) { zrowA[idx] = 0u; zrowB[idx] = 0u; }
    if (idx == 256) rowptr[n] = E;   // sentinel
}

// ---------------- MFMA GEMM ----------------
// block 256 = 4 waves; tile 64 rows x 128 cols; wave w: rows w*16..+15.
// in_bf16: A-fragments read directly from packed-bf16 global rows.
// out_mode 1: packed-bf16 rows, each row scaled by oscale[row] if given (dinv prescale).
// out_mode 2: +bias, softmax over first KOUT cols, f32 [nrows, KOUT] output.

__launch_bounds__(256)
__global__ void gemm_mfma_kernel(const void* __restrict__ Xin, const unsigned short* __restrict__ Wf,
                                 const float* __restrict__ bias, const float* __restrict__ oscale,
                                 void* __restrict__ Y, int nrows, int in_bf16, int out_mode) {
    __shared__ float lds_f[64 * 130];                      // 33280 B
    unsigned short* lds_h = (unsigned short*)lds_f;
    unsigned int* lds_u = (unsigned int*)lds_f;

    int tid = threadIdx.x;
    int w = tid >> 6, lane = tid & 63;
    int quad = lane >> 4, m16 = lane & 15;
    int r0 = blockIdx.x * 64;

    if (!in_bf16) {
        int row = tid >> 2, cg_ = tid & 3;
        bool valid = (r0 + row) < nrows;
        const float4* Xr = (const float4*)Xin + (size_t)(r0 + row) * 32 + cg_ * 8;
#pragma unroll
        for (int j = 0; j < 8; j++) {
            float4 v = valid ? Xr[j] : make_float4(0.f, 0.f, 0.f, 0.f);
            int c = cg_ * 32 + j * 4;
            lds_u[row * 68 + (c >> 1)]     = pack_bf(v.x, v.y);
            lds_u[row * 68 + (c >> 1) + 1] = pack_bf(v.z, v.w);
        }
        __syncthreads();
    }

    floatx4 acc[8];
#pragma unroll
    for (int ct = 0; ct < 8; ct++) acc[ct] = (floatx4){0.f, 0.f, 0.f, 0.f};

    int arow = r0 + w * 16 + m16;
    if (arow > nrows - 1) arow = nrows - 1;
    const unsigned int* Xb = (const unsigned int*)Xin;

    const short8* Wf8 = (const short8*)Wf;
#pragma unroll
    for (int kt = 0; kt < 4; kt++) {
        short8 a;
        if (in_bf16) {
            a = *(const short8*)(Xb + (size_t)arow * 64 + kt * 16 + quad * 4);
        } else {
            a = *(const short8*)(lds_h + (w * 16 + m16) * 136 + kt * 32 + quad * 8);
        }
#pragma unroll
        for (int ct = 0; ct < 8; ct++) {
            short8 b = Wf8[(kt * 8 + ct) * 64 + lane];
            acc[ct] = __builtin_amdgcn_mfma_f32_16x16x32_bf16(a, b, acc[ct], 0, 0, 0);
        }
    }

    if (out_mode == 1) {
        __syncthreads();   // reuse LDS as f32 out staging [64][130]
#pragma unroll
        for (int ct = 0; ct < 8; ct++) {
#pragma unroll
            for (int r = 0; r < 4; r++) {
                int rl = w * 16 + quad * 4 + r;
                lds_f[rl * 130 + ct * 16 + m16] = acc[ct][r];
            }
        }
        __syncthreads();
        unsigned int* Yb = (unsigned int*)Y;
        for (int r = 0; r < 16; r++) {
            int row = r0 + w * 16 + r;
            if (row < nrows) {
                float sc = oscale ? oscale[row] : 1.f;
                float lo = lds_f[(w * 16 + r) * 130 + 2 * lane] * sc;
                float hi = lds_f[(w * 16 + r) * 130 + 2 * lane + 1] * sc;
                Yb[(size_t)row * 64 + lane] = pack_bf(lo, hi);
            }
        }
    } else {
        // out_mode 2: bias + softmax over cols < KOUT, f32 output [nrows, KOUT]
        float bb[8];
#pragma unroll
        for (int ct = 0; ct < 8; ct++) bb[ct] = bias[ct * 16 + m16];
        float* Yf = (float*)Y;
#pragma unroll
        for (int r = 0; r < 4; r++) {
            int row = r0 + w * 16 + quad * 4 + r;
            float vv[8];
            float mx = -1e30f;
#pragma unroll
            for (int ct = 0; ct < 8; ct++) {
                int col = ct * 16 + m16;
                vv[ct] = (col < KOUT) ? acc[ct][r] + bb[ct] : -1e30f;
                mx = fmaxf(mx, vv[ct]);
            }
#pragma unroll
            for (int off = 1; off < 16; off <<= 1) mx = fmaxf(mx, __shfl_xor(mx, off));
            float se = 0.f;
#pragma unroll
            for (int ct = 0; ct < 8; ct++) {
                vv[ct] = (vv[ct] > -1e29f) ? __expf(vv[ct] - mx) : 0.f;
                se += vv[ct];
            }
#pragma unroll
            for (int off = 1; off < 16; off <<= 1) se += __shfl_xor(se, off);
            float inv = 1.f / se;
            if (row < nrows) {
#pragma unroll
                for (int ct = 0; ct < 8; ct++) {
                    int col = ct * 16 + m16;
                    if (col < KOUT) Yf[(size_t)row * KOUT + col] = vv[ct] * inv;
                }
            }
        }
    }
}

// ---------------- Aggregate (r0-exact structure, proven 46.2 us) ----------------
// Ob[i] = bf16( post(di*(sum Hb'[src] + Hb'[i]) + b) ); rows dinv[src]-prescaled.
// one wave per node; 4 groups of 16 lanes, group = 1 edge, lane = uint4 (8 feats).
// software-pipelined: next iteration's indices load while current gathers in flight.
// masked tail points at zero-row index n. cnt from rowptr pair (sentinel rowptr[n]=E).
// post_scale: multiply final by di again (folds the dinv prescale that GEMM2's
// epilogue used to apply, now that GEMM2 is algebraically eliminated).

__launch_bounds__(256)
__global__ void aggregate_kernel(const uint4* __restrict__ Hb4, const int* __restrict__ csr,
                                 const int* __restrict__ rowptr,
                                 const float* __restrict__ dinv, const float* __restrict__ bias,
                                 unsigned int* __restrict__ Ob, int n, int do_relu, int post_scale) {
    int wid = threadIdx.x >> 6, lane = threadIdx.x & 63;
    int g = lane >> 4, c = lane & 15;
    int i = blockIdx.x * 4 + wid;
    if (i >= n) return;

    float di = dinv[i];
    int start = rowptr[i];
    int cnt = rowptr[i + 1] - start;
    const int* cp = csr + start;

    float acc[8];
    {   // self term (group 0 only)
        uint4 sv = Hb4[(size_t)i * 16 + c];
        unsigned int su[4] = {sv.x, sv.y, sv.z, sv.w};
        if (g != 0) { su[0] = su[1] = su[2] = su[3] = 0u; }
#pragma unroll
        for (int t = 0; t < 4; t++) {
            acc[2 * t]     = bf_lo(su[t]);
            acc[2 * t + 1] = bf_hi(su[t]);
        }
    }

    int s[4];
#pragma unroll
    for (int u = 0; u < 4; u++) {
        int idx = u * 4 + g;
        s[u] = (idx < cnt) ? cp[idx] : n;          // n = zero row
    }
    for (int e = 0; e < cnt; e += 16) {
        uint4 v[4];
#pragma unroll
        for (int u = 0; u < 4; u++) v[u] = Hb4[(size_t)s[u] * 16 + c];
        int ns[4];
#pragma unroll
        for (int u = 0; u < 4; u++) {
            int idx = e + 16 + u * 4 + g;
            ns[u] = (idx < cnt) ? cp[idx] : n;
        }
#pragma unroll
        for (int u = 0; u < 4; u++) {
            unsigned int uu[4] = {v[u].x, v[u].y, v[u].z, v[u].w};
#pragma unroll
            for (int t = 0; t < 4; t++) {
                acc[2 * t]     += bf_lo(uu[t]);
                acc[2 * t + 1] += bf_hi(uu[t]);
            }
        }
#pragma unroll
        for (int u = 0; u < 4; u++) s[u] = ns[u];
    }

    // butterfly across the 4 groups (lane bits 4,5)
#pragma unroll
    for (int j = 0; j < 8; j++) {
        acc[j] += __shfl_xor(acc[j], 16);
        acc[j] += __shfl_xor(acc[j], 32);
    }

    // lane (g,c) writes feature pair p = c*4+g (feats 8c+2g, 8c+2g+1)
    float2 bb = bias ? ((const float2*)bias)[c * 4 + g] : make_float2(0.f, 0.f);
    float fx = acc[g * 2]     * di + bb.x;
    float fy = acc[g * 2 + 1] * di + bb.y;
    if (do_relu) { fx = fmaxf(fx, 0.f); fy = fmaxf(fy, 0.f); }
    if (post_scale) { fx *= di; fy *= di; }
    Ob[(size_t)i * 64 + c * 4 + g] = pack_bf(fx, fy);
}

// ---------------- launch ----------------

extern "C" void kernel_launch(void* const* d_in, const int* in_sizes, int n_in,
                              void* d_out, int out_size, void* d_ws, size_t ws_size,
                              hipStream_t stream) {
    const float* x  = (const float*)d_in[0];
    const int*   ei = (const int*)d_in[1];     // [2,E] int32
    const float* W1 = (const float*)d_in[2];
    const float* b1 = (const float*)d_in[3];
    const float* W2 = (const float*)d_in[4];
    const float* b2 = (const float*)d_in[5];
    const float* Wa = (const float*)d_in[6];
    const float* ba = (const float*)d_in[7];
    float* out = (float*)d_out;

    int N = in_sizes[0] / D;
    int E = in_sizes[1] / 2;

    int nbuck = (N + 255) >> 8;                       // 196 for N=50000
    int cap = ((E / nbuck) + 2048 + 63) & ~63;

    char* w = (char*)d_ws;
    size_t off = 0;
    auto carve = [&](size_t bytes) -> void* {
        void* p = w + off;
        off = (off + bytes + 255) & ~(size_t)255;
        return p;
    };
    float* dinv   = (float*)carve((size_t)N * 4);
    int*   rowptr = (int*)carve((size_t)(N + 1) * 4);
    int*   bcur   = (int*)carve(256 * 4);
    unsigned int* bdata = (unsigned int*)carve((size_t)nbuck * cap * 4);
    int*   csr    = (int*)carve((size_t)E * 4);
    unsigned short* Wf1 = (unsigned short*)carve(16384 * 2);
    unsigned short* WfF = (unsigned short*)carve(16384 * 2);
    float* bpad   = (float*)carve(512);
    unsigned int* HbA = (unsigned int*)carve((size_t)(N + 1) * 64 * 4);  // +1 zero row
    unsigned int* HbB = (unsigned int*)carve((size_t)(N + 1) * 64 * 4);
    (void)ws_size; (void)n_in; (void)out_size;

    int nbNode4 = (N + 3) / 4;
    int nbGemm = (N + 63) / 64;
    int nbP1 = (E + CHUNK - 1) / CHUNK;

    prep_frag_kernel<<<128, 256, 0, stream>>>(W1, W2, Wa, ba, b2, Wf1, WfF, bpad,
                                              bcur, rowptr,
                                              HbA + (size_t)N * 64, HbB + (size_t)N * 64, N, E);
    bucket_pass1<<<nbP1, 256, 0, stream>>>(ei, E, nbuck, cap, bcur, bdata);
    bucket_build<<<nbuck, 256, 0, stream>>>(bdata, bcur, cap, dinv, rowptr, csr, N, nbuck);

    // layer 1: gemm writes bf16(dinv_j * (X W1)_j) rows
    gemm_mfma_kernel<<<nbGemm, 256, 0, stream>>>(x, Wf1, nullptr, dinv, HbA, N, 0, 1);
    // agg1: h1p_i = bf16( dinv_i * relu(acc*dinv_i + b1) )   (post_scale folds prescale)
    aggregate_kernel<<<nbNode4, 256, 0, stream>>>((const uint4*)HbA, csr, rowptr, dinv, b1, HbB, N, 1, 1);
    // agg2: G_i = bf16( dinv_i * acc )   (no bias, no relu; feeds fused GEMM)
    aggregate_kernel<<<nbNode4, 256, 0, stream>>>((const uint4*)HbB, csr, rowptr, dinv, nullptr, HbA, N, 0, 0);
    // fused attention: out = softmax( G @ (W2@Wa) + (b2@Wa + ba) )
    gemm_mfma_kernel<<<nbGemm, 256, 0, stream>>>(HbA, WfF, bpad, nullptr, out, N, 1, 2);
}